// Round 1
// baseline (387.368 us; speedup 1.0000x reference)
//
#include <hip/hip_runtime.h>
#include <hip/hip_bf16.h>

// SampleContrastiveLoss on MI355X.
// N = 16384 rows (derived from in_sizes[2]), D = 128.
// ws layout:
//   [0,      4 MB)  n0 bf16  (N*128 u16)
//   [4 MB,   8 MB)  n1 bf16
//   [8 MB,  +64KB)  diag f32[N]   (dot(n0_i, n1_i), fp32)
//   [+64KB, +64KB)  den  f32[N]   (masked denominator sums)
//   [+64KB, +64KB)  maskf f32[N]  (mask as 0.0/1.0)

#define DD 128
#define INV_T 14.285714285714286f   // 1/0.07

typedef __attribute__((ext_vector_type(8))) short bf16x8; // 8 bf16 = 4 VGPR
typedef __attribute__((ext_vector_type(4))) float f32x4;
typedef unsigned short u16;
typedef unsigned char u8;

__device__ __forceinline__ u16 f2bf(float x) {   // RNE f32->bf16
    union { float f; unsigned u; } v; v.f = x;
    unsigned r = v.u + 0x7fffu + ((v.u >> 16) & 1u);
    return (u16)(r >> 16);
}

// ---- mask dtype detection + conversion to float -------------------------
// If mask uploaded as u8 (numpy bool), bytes at p%4!=0 are ~50% ones.
// If uploaded as int32 (0/1 little-endian), those bytes are ALL zero.
__global__ void maskprep_kernel(const u8* __restrict__ mraw,
                                float* __restrict__ maskf, int n) {
    __shared__ int s_any;
    if (threadIdx.x == 0) s_any = 0;
    __syncthreads();
    int local = 0;
    for (int p = threadIdx.x; p < n; p += blockDim.x)
        if ((p & 3) && mraw[p]) local = 1;
    if (local) atomicOr(&s_any, 1);
    __syncthreads();
    const bool is_u8 = (s_any != 0);
    const int* mi = (const int*)mraw;
    for (int j = threadIdx.x; j < n; j += blockDim.x) {
        int v = is_u8 ? (int)mraw[j] : mi[j];
        maskf[j] = v ? 1.0f : 0.0f;
    }
}

// ---- per-row L2 normalize -> bf16, fp32 diag dot, zero den --------------
__global__ __launch_bounds__(256) void norm_kernel(
        const float* __restrict__ f0, const float* __restrict__ f1,
        u16* __restrict__ n0b, u16* __restrict__ n1b,
        float* __restrict__ diag, float* __restrict__ den) {
    const int wave = threadIdx.x >> 6, lane = threadIdx.x & 63;
    const int i = blockIdx.x * 4 + wave;
    const float2 a = *(const float2*)(f0 + (size_t)i * DD + lane * 2);
    const float2 b = *(const float2*)(f1 + (size_t)i * DD + lane * 2);
    float s0 = a.x * a.x + a.y * a.y;
    float s1 = b.x * b.x + b.y * b.y;
    float d  = a.x * b.x + a.y * b.y;
    #pragma unroll
    for (int off = 32; off; off >>= 1) {
        s0 += __shfl_xor(s0, off);
        s1 += __shfl_xor(s1, off);
        d  += __shfl_xor(d,  off);
    }
    const float r0 = 1.0f / fmaxf(sqrtf(s0), 1e-12f);
    const float r1 = 1.0f / fmaxf(sqrtf(s1), 1e-12f);
    ushort2 t0; t0.x = f2bf(a.x * r0); t0.y = f2bf(a.y * r0);
    ushort2 t1; t1.x = f2bf(b.x * r1); t1.y = f2bf(b.y * r1);
    *(ushort2*)(n0b + (size_t)i * DD + lane * 2) = t0;
    *(ushort2*)(n1b + (size_t)i * DD + lane * 2) = t1;
    if (lane == 0) { diag[i] = d * r0 * r1; den[i] = 0.0f; }
}

// ---- fused sim-tile GEMM + exp + masked row-sum -------------------------
// 128x128 output tile / block; K = 128 (whole D, single stage).
// LDS layout: row-major [128][128] bf16 with 16B-chunk XOR swizzle
//   chunk' = chunk ^ (row & 7)   (involution; applied at SOURCE of
//   global_load_lds and at ds_read -> conflict-free reads, rule #21).
__global__ __launch_bounds__(256) void gemm_kernel(
        const u16* __restrict__ n0b, const u16* __restrict__ n1b,
        const float* __restrict__ maskf, float* __restrict__ den) {
    __shared__ u16 As[128 * 128];
    __shared__ u16 Bs[128 * 128];
    const int tid  = threadIdx.x;
    const int wave = tid >> 6, lane = tid & 63;
    const int iblk = blockIdx.y, jblk = blockIdx.x;

    {   // stage: contiguous 32KB slab each, source-swizzled, width-16 DMA
        const char* gA = (const char*)(n0b + (size_t)iblk * 128 * DD);
        const char* gB = (const char*)(n1b + (size_t)jblk * 128 * DD);
        char* lA = (char*)As;
        char* lB = (char*)Bs;
        #pragma unroll
        for (int it = 0; it < 8; ++it) {
            const int ldsOff = it * 4096 + wave * 1024;   // wave-uniform
            const int chunk  = (ldsOff >> 4) + lane;
            const int row    = chunk >> 4;
            const int c      = chunk & 15;
            const int src    = row * 256 + ((c ^ (row & 7)) << 4);
            __builtin_amdgcn_global_load_lds(
                (const __attribute__((address_space(1))) unsigned int*)(gA + src),
                (__attribute__((address_space(3))) unsigned int*)(lA + ldsOff),
                16, 0, 0);
            __builtin_amdgcn_global_load_lds(
                (const __attribute__((address_space(1))) unsigned int*)(gB + src),
                (__attribute__((address_space(3))) unsigned int*)(lB + ldsOff),
                16, 0, 0);
        }
    }
    __syncthreads();

    const int wr = wave >> 1, wc = wave & 1;      // 2x2 wave grid, 64x64 each
    const int lr = lane & 15, lk = lane >> 4;

    float mv[4];
    #pragma unroll
    for (int n = 0; n < 4; ++n)
        mv[n] = maskf[jblk * 128 + wc * 64 + n * 16 + lr];

    f32x4 acc[4][4] = {};
    const char* Ab = (const char*)As;
    const char* Bb = (const char*)Bs;
    #pragma unroll
    for (int kk = 0; kk < 4; ++kk) {
        const int byteoff = kk * 64 + lk * 16;
        bf16x8 af[4], bfr[4];
        #pragma unroll
        for (int m = 0; m < 4; ++m) {
            const int r = wr * 64 + m * 16 + lr;
            af[m] = *(const bf16x8*)(Ab + r * 256 + (byteoff ^ ((r & 7) << 4)));
        }
        #pragma unroll
        for (int n = 0; n < 4; ++n) {
            const int r = wc * 64 + n * 16 + lr;
            bfr[n] = *(const bf16x8*)(Bb + r * 256 + (byteoff ^ ((r & 7) << 4)));
        }
        #pragma unroll
        for (int m = 0; m < 4; ++m)
            #pragma unroll
            for (int n = 0; n < 4; ++n)
                acc[m][n] = __builtin_amdgcn_mfma_f32_16x16x32_bf16(
                                af[m], bfr[n], acc[m][n], 0, 0, 0);
    }

    // epilogue: exp(sim/T)*mask, reduce over the 16 col-lanes, atomic row add
    #pragma unroll
    for (int m = 0; m < 4; ++m) {
        #pragma unroll
        for (int reg = 0; reg < 4; ++reg) {
            float s = 0.0f;
            #pragma unroll
            for (int n = 0; n < 4; ++n)
                s += __expf(acc[m][n][reg] * INV_T) * mv[n];
            s += __shfl_xor(s, 1);
            s += __shfl_xor(s, 2);
            s += __shfl_xor(s, 4);
            s += __shfl_xor(s, 8);
            if (lr == 0) {
                const int ig = iblk * 128 + wr * 64 + m * 16 + lk * 4 + reg;
                atomicAdd(&den[ig], s);
            }
        }
    }
}

// ---- final masked loss reduction ---------------------------------------
__global__ __launch_bounds__(256) void final_kernel(
        const float* __restrict__ diag, const float* __restrict__ den,
        const float* __restrict__ maskf, float* __restrict__ out, int n) {
    double ls = 0.0, cs = 0.0;
    for (int i = threadIdx.x; i < n; i += 256) {
        const float m = maskf[i];
        const float num = expf(diag[i] * INV_T);
        const float l = logf(den[i] + 1e-8f) - logf(num + 1e-8f);
        ls += (double)(m * l);
        cs += (double)m;
    }
    #pragma unroll
    for (int off = 32; off; off >>= 1) {
        ls += __shfl_xor(ls, off);
        cs += __shfl_xor(cs, off);
    }
    __shared__ double sl[4], sc[4];
    const int wave = threadIdx.x >> 6, lane = threadIdx.x & 63;
    if (lane == 0) { sl[wave] = ls; sc[wave] = cs; }
    __syncthreads();
    if (threadIdx.x == 0) {
        const double L = sl[0] + sl[1] + sl[2] + sl[3];
        const double C = sc[0] + sc[1] + sc[2] + sc[3];
        out[0] = (float)(L / C);
    }
}

extern "C" void kernel_launch(void* const* d_in, const int* in_sizes, int n_in,
                              void* d_out, int out_size, void* d_ws, size_t ws_size,
                              hipStream_t stream) {
    const float* f0 = (const float*)d_in[0];
    const float* f1 = (const float*)d_in[1];
    const u8*  mraw = (const u8*)d_in[2];
    float* out = (float*)d_out;

    const int N = in_sizes[2];            // 16384
    char* ws = (char*)d_ws;
    u16*   n0b   = (u16*)ws;
    u16*   n1b   = (u16*)(ws + (size_t)4 * 1024 * 1024);
    float* diag  = (float*)(ws + (size_t)8 * 1024 * 1024);
    float* den   = diag + N;
    float* maskf = den + N;

    maskprep_kernel<<<1, 1024, 0, stream>>>(mraw, maskf, N);
    norm_kernel<<<N / 4, 256, 0, stream>>>(f0, f1, n0b, n1b, diag, den);
    gemm_kernel<<<dim3(N / 128, N / 128), 256, 0, stream>>>(n0b, n1b, maskf, den);
    final_kernel<<<1, 256, 0, stream>>>(diag, den, maskf, out, N);
}

// Round 2
// 224.540 us; speedup vs baseline: 1.7252x; 1.7252x over previous
//
#include <hip/hip_runtime.h>
#include <hip/hip_bf16.h>

// SampleContrastiveLoss on MI355X — round 2.
// N = 16384, D = 128. Mask-compacted denominator GEMM:
//   den_i = sum_{j masked} exp(sim_ij / T)
// Bc = gathered+padded n1 rows, PRE-SCALED by C = (1/T)*log2(e) so the MFMA
// accumulator is already the exp2 argument.
//
// ws layout:
//   [0,      4 MB)   n0b  bf16 [N][128]      (A side, unscaled)
//   [4 MB,   8 MB)   Bc   bf16 [N][128]      (compacted masked n1 rows, scaled)
//   [8 MB,  +64KB)   diag f32[N]             (fp32 dot(n0_i, n1_i))
//   [+64KB, +64KB)   maskf f32[N]
//   [+64KB, +64KB)   wc   f32[N]             (compacted col weight, 1/0)
//   [+64KB, +64KB)   den  f32[N]
//   [+4B]            cnt  int                (compacted count)

#define DD 128
#define INV_T 14.285714285714286f
#define C_EXP2 20.6099291555566f   // INV_T * log2(e)
#define JSL 4                      // j-slices per i-block

typedef __attribute__((ext_vector_type(8))) short bf16x8; // 8 bf16 = 4 VGPR
typedef __attribute__((ext_vector_type(4))) float f32x4;
typedef unsigned short u16;
typedef unsigned char u8;

__device__ __forceinline__ u16 f2bf(float x) {   // RNE f32->bf16
    union { float f; unsigned u; } v; v.f = x;
    unsigned r = v.u + 0x7fffu + ((v.u >> 16) & 1u);
    return (u16)(r >> 16);
}

__device__ __forceinline__ float fast_exp2(float x) {
#if __has_builtin(__builtin_amdgcn_exp2f)
    return __builtin_amdgcn_exp2f(x);     // raw v_exp_f32
#else
    return exp2f(x);
#endif
}

// ---- mask dtype detect + init maskf/wc/den/cnt --------------------------
// bool-as-u8: bytes at p%4!=0 in the first 4KB are ~50% nonzero.
// int32 0/1 LE: those bytes are all zero. Every block computes the same flag.
__global__ __launch_bounds__(256) void prep_kernel(
        const u8* __restrict__ mraw, float* __restrict__ maskf,
        float* __restrict__ wc, float* __restrict__ den,
        int* __restrict__ cnt, int n) {
    __shared__ int s_any;
    if (threadIdx.x == 0) s_any = 0;
    __syncthreads();
    int local = 0;
    #pragma unroll
    for (int q = 0; q < 16; ++q) {
        const int p = threadIdx.x * 16 + q;
        if ((p & 3) && mraw[p]) local = 1;
    }
    if (local) atomicOr(&s_any, 1);
    __syncthreads();
    const bool is_u8 = (s_any != 0);
    const int* mi = (const int*)mraw;
    const int idx0 = blockIdx.x * 256 + threadIdx.x;
    const int stride = gridDim.x * 256;
    for (int j = idx0; j < n; j += stride) {
        const int v = is_u8 ? (int)mraw[j] : mi[j];
        maskf[j] = v ? 1.0f : 0.0f;
        wc[j] = 0.0f;
        den[j] = 0.0f;
    }
    if (idx0 == 0) *cnt = 0;
}

// ---- per-row L2 normalize; write A (bf16), scatter masked scaled B ------
__global__ __launch_bounds__(256) void norm_kernel(
        const float* __restrict__ f0, const float* __restrict__ f1,
        const float* __restrict__ maskf,
        u16* __restrict__ n0b, u16* __restrict__ Bc, float* __restrict__ wc,
        float* __restrict__ diag, int* __restrict__ cnt) {
    const int wave = threadIdx.x >> 6, lane = threadIdx.x & 63;
    const int i = blockIdx.x * 4 + wave;
    const float2 a = *(const float2*)(f0 + (size_t)i * DD + lane * 2);
    const float2 b = *(const float2*)(f1 + (size_t)i * DD + lane * 2);
    float s0 = a.x * a.x + a.y * a.y;
    float s1 = b.x * b.x + b.y * b.y;
    float d  = a.x * b.x + a.y * b.y;
    #pragma unroll
    for (int off = 32; off; off >>= 1) {
        s0 += __shfl_xor(s0, off);
        s1 += __shfl_xor(s1, off);
        d  += __shfl_xor(d,  off);
    }
    const float r0 = 1.0f / fmaxf(sqrtf(s0), 1e-12f);
    const float r1 = 1.0f / fmaxf(sqrtf(s1), 1e-12f);
    ushort2 t0; t0.x = f2bf(a.x * r0); t0.y = f2bf(a.y * r0);
    *(ushort2*)(n0b + (size_t)i * DD + lane * 2) = t0;
    if (maskf[i] != 0.0f) {
        int pos;
        if (lane == 0) pos = atomicAdd(cnt, 1);
        pos = __shfl(pos, 0);
        const float sc = r1 * C_EXP2;
        ushort2 t1; t1.x = f2bf(b.x * sc); t1.y = f2bf(b.y * sc);
        *(ushort2*)(Bc + (size_t)pos * DD + lane * 2) = t1;
        if (lane == 0) wc[pos] = 1.0f;
    }
    if (lane == 0) diag[i] = d * r0 * r1;
}

// ---- B-tile DMA stage, source-swizzled (16B-chunk XOR, rule #21) --------
__device__ __forceinline__ void stage_tile(u16* dst, const u16* src,
                                           int wave, int lane) {
    char* lB = (char*)dst;
    const char* gB = (const char*)src;
    #pragma unroll
    for (int it = 0; it < 8; ++it) {
        const int ldsOff = it * 4096 + wave * 1024;      // wave-uniform base
        const int chunk  = (ldsOff >> 4) + lane;         // HW: dst + lane*16
        const int row    = chunk >> 4;
        const int c      = chunk & 15;
        const int srcOff = row * 256 + ((c ^ (row & 7)) << 4);
        __builtin_amdgcn_global_load_lds(
            (const __attribute__((address_space(1))) unsigned int*)(gB + srcOff),
            (__attribute__((address_space(3))) unsigned int*)(lB + ldsOff),
            16, 0, 0);
    }
}

// ---- main fused kernel: A-in-regs, B LDS double-buffered ----------------
// grid = (JSL, N/128). Block owns 128 i-rows × one j-slice of compacted cols.
// Wave tile 64x64 (2x2 wave grid). den accumulated in registers across the
// whole slice; epilogue: den += exp2(acc) * w   (B pre-scaled by C_EXP2).
__global__ __launch_bounds__(256, 2) void gemm_kernel(
        const u16* __restrict__ n0b, const u16* __restrict__ Bc,
        const float* __restrict__ wc, const int* __restrict__ cnt,
        float* __restrict__ den) {
    __shared__ u16 Bs[2][128 * 128];
    const int tid  = threadIdx.x;
    const int wave = tid >> 6, lane = tid & 63;
    const int jsl = blockIdx.x, iblk = blockIdx.y;
    const int wr = wave >> 1, wq = wave & 1;     // 2x2 wave grid
    const int lr = lane & 15, lk = lane >> 4;

    const int c = *cnt;
    const int ntiles = (c + 127) >> 7;
    const int per = (ntiles + JSL - 1) / JSL;
    const int t0 = jsl * per;
    const int t1 = min(ntiles, t0 + per);

    // A fragments: rows (iblk*128 + wr*64 + m*16 + lr), K chunk (kk*32+lk*8)
    bf16x8 af[4][4];
    #pragma unroll
    for (int m = 0; m < 4; ++m) {
        const int r = iblk * 128 + wr * 64 + m * 16 + lr;
        const char* rowp = (const char*)(n0b + (size_t)r * DD);
        #pragma unroll
        for (int kk = 0; kk < 4; ++kk)
            af[m][kk] = *(const bf16x8*)(rowp + kk * 64 + lk * 16);
    }

    float dacc[4][4] = {};   // [m][reg] per-lane col-partial denominators

    if (t0 < t1) {
        stage_tile(Bs[0], Bc + (size_t)t0 * DD * 128, wave, lane);
        __syncthreads();
        int cur = 0;
        for (int t = t0; t < t1; ++t) {
            if (t + 1 < t1)
                stage_tile(Bs[cur ^ 1], Bc + (size_t)(t + 1) * DD * 128, wave, lane);

            float wv[4];
            #pragma unroll
            for (int nn = 0; nn < 4; ++nn)
                wv[nn] = wc[t * 128 + wq * 64 + nn * 16 + lr];

            f32x4 acc[4][4] = {};
            const char* Bb = (const char*)Bs[cur];
            #pragma unroll
            for (int kk = 0; kk < 4; ++kk) {
                const int byteoff = kk * 64 + lk * 16;
                bf16x8 bfr[4];
                #pragma unroll
                for (int nn = 0; nn < 4; ++nn) {
                    const int rr = wq * 64 + nn * 16 + lr;
                    bfr[nn] = *(const bf16x8*)(Bb + rr * 256 + (byteoff ^ ((rr & 7) << 4)));
                }
                #pragma unroll
                for (int m = 0; m < 4; ++m)
                    #pragma unroll
                    for (int nn = 0; nn < 4; ++nn)
                        acc[m][nn] = __builtin_amdgcn_mfma_f32_16x16x32_bf16(
                                        af[m][kk], bfr[nn], acc[m][nn], 0, 0, 0);
            }

            // epilogue: den += exp2(sim*C) * w   (2 VALU ops / element)
            #pragma unroll
            for (int m = 0; m < 4; ++m)
                #pragma unroll
                for (int reg = 0; reg < 4; ++reg) {
                    float s = dacc[m][reg];
                    #pragma unroll
                    for (int nn = 0; nn < 4; ++nn)
                        s += fast_exp2(acc[m][nn][reg]) * wv[nn];
                    dacc[m][reg] = s;
                }
            __syncthreads();
            cur ^= 1;
        }
    }

    // reduce col-partials across the 16 lr-lanes; 1 atomic per (row, wave)
    #pragma unroll
    for (int m = 0; m < 4; ++m)
        #pragma unroll
        for (int reg = 0; reg < 4; ++reg) {
            float s = dacc[m][reg];
            s += __shfl_xor(s, 1);
            s += __shfl_xor(s, 2);
            s += __shfl_xor(s, 4);
            s += __shfl_xor(s, 8);
            if (lr == 0)
                atomicAdd(&den[iblk * 128 + wr * 64 + m * 16 + lk * 4 + reg], s);
        }
}

// ---- final masked loss reduction ---------------------------------------
__global__ __launch_bounds__(256) void final_kernel(
        const float* __restrict__ diag, const float* __restrict__ den,
        const float* __restrict__ maskf, float* __restrict__ out, int n) {
    double ls = 0.0, cs = 0.0;
    for (int i = threadIdx.x; i < n; i += 256) {
        const float m = maskf[i];
        const float num = expf(diag[i] * INV_T);
        const float l = logf(den[i] + 1e-8f) - logf(num + 1e-8f);
        ls += (double)(m * l);
        cs += (double)m;
    }
    #pragma unroll
    for (int off = 32; off; off >>= 1) {
        ls += __shfl_xor(ls, off);
        cs += __shfl_xor(cs, off);
    }
    __shared__ double sl[4], sc[4];
    const int wave = threadIdx.x >> 6, lane = threadIdx.x & 63;
    if (lane == 0) { sl[wave] = ls; sc[wave] = cs; }
    __syncthreads();
    if (threadIdx.x == 0) {
        const double L = sl[0] + sl[1] + sl[2] + sl[3];
        const double C = sc[0] + sc[1] + sc[2] + sc[3];
        out[0] = (float)(L / C);
    }
}

extern "C" void kernel_launch(void* const* d_in, const int* in_sizes, int n_in,
                              void* d_out, int out_size, void* d_ws, size_t ws_size,
                              hipStream_t stream) {
    const float* f0 = (const float*)d_in[0];
    const float* f1 = (const float*)d_in[1];
    const u8*  mraw = (const u8*)d_in[2];
    float* out = (float*)d_out;

    const int N = in_sizes[2];            // 16384
    char* ws = (char*)d_ws;
    u16*   n0b   = (u16*)ws;
    u16*   Bc    = (u16*)(ws + (size_t)4 * 1024 * 1024);
    float* diag  = (float*)(ws + (size_t)8 * 1024 * 1024);
    float* maskf = diag + N;
    float* wc    = maskf + N;
    float* den   = wc + N;
    int*   cnt   = (int*)(den + N);

    prep_kernel<<<64, 256, 0, stream>>>(mraw, maskf, wc, den, cnt, N);
    norm_kernel<<<N / 4, 256, 0, stream>>>(f0, f1, maskf, n0b, Bc, wc, diag, cnt);
    gemm_kernel<<<dim3(JSL, N / 128), 256, 0, stream>>>(n0b, Bc, wc, cnt, den);
    final_kernel<<<1, 256, 0, stream>>>(diag, den, maskf, out, N);
}

// Round 3
// 118.628 us; speedup vs baseline: 3.2654x; 1.8928x over previous
//
#include <hip/hip_runtime.h>
#include <hip/hip_bf16.h>

// SampleContrastiveLoss on MI355X — round 3.
// N = 16384, D = 128. Mask-compacted denominator GEMM:
//   den_i = sum_{j masked} exp(sim_ij / T)
// Bc = gathered+padded n1 rows, PRE-SCALED by C = (1/T)*log2(e) so the MFMA
// accumulator is already the exp2 argument.
// Round-3 deltas: block-scan compaction (64 atomics, was 8192 serialized),
// norm reads pos[] (pure streaming), parallel double-atomic final reduce.
//
// ws layout:
//   [0,      4 MB)   n0b  bf16 [N][128]
//   [4 MB,   8 MB)   Bc   bf16 [N][128]  (compacted masked n1 rows, scaled)
//   [8 MB, ...)      diag f32[N] | maskf f32[N] | wc f32[N] | den f32[N]
//                    | pos i32[N] | {cnt i32, pad, Lsum f64, Csum f64}

#define DD 128
#define INV_T 14.285714285714286f
#define C_EXP2 20.6099291555566f   // INV_T * log2(e)
#define JSL 4                      // j-slices per i-block

typedef __attribute__((ext_vector_type(8))) short bf16x8; // 8 bf16 = 4 VGPR
typedef __attribute__((ext_vector_type(4))) float f32x4;
typedef unsigned short u16;
typedef unsigned char u8;

__device__ __forceinline__ u16 f2bf(float x) {   // RNE f32->bf16
    union { float f; unsigned u; } v; v.f = x;
    unsigned r = v.u + 0x7fffu + ((v.u >> 16) & 1u);
    return (u16)(r >> 16);
}

__device__ __forceinline__ float fast_exp2(float x) {
#if __has_builtin(__builtin_amdgcn_exp2f)
    return __builtin_amdgcn_exp2f(x);     // raw v_exp_f32
#else
    return exp2f(x);
#endif
}

// ---- mask dtype detect + maskf/wc/den init + block-scan compaction ------
// bool-as-u8: bytes at p%4!=0 in the first 4KB are ~50% nonzero.
// int32 0/1 LE: those bytes are all zero. Every block derives the same flag.
// grid = N/256 blocks x 256 threads; one row per thread.
__global__ __launch_bounds__(256) void prep_kernel(
        const u8* __restrict__ mraw, float* __restrict__ maskf,
        float* __restrict__ wc, float* __restrict__ den,
        int* __restrict__ pos, int* __restrict__ cnt, int n) {
    __shared__ int s_any;
    __shared__ int s_wsum[4];
    __shared__ int s_base;
    if (threadIdx.x == 0) s_any = 0;
    __syncthreads();
    int local = 0;
    #pragma unroll
    for (int q = 0; q < 16; ++q) {
        const int p = threadIdx.x * 16 + q;
        if ((p & 3) && mraw[p]) local = 1;
    }
    if (local) atomicOr(&s_any, 1);
    __syncthreads();
    const bool is_u8 = (s_any != 0);
    const int* mi = (const int*)mraw;

    const int i = blockIdx.x * 256 + threadIdx.x;
    const int v = is_u8 ? (int)mraw[i] : mi[i];
    const int m = v ? 1 : 0;
    maskf[i] = (float)m;
    wc[i]   = 0.0f;
    den[i]  = 0.0f;

    const int wave = threadIdx.x >> 6, lane = threadIdx.x & 63;
    const unsigned long long bal = __ballot(m);
    const int wprefix = __popcll(bal & ((1ULL << lane) - 1ULL));
    const int wtotal  = __popcll(bal);
    if (lane == 0) s_wsum[wave] = wtotal;
    __syncthreads();
    if (threadIdx.x == 0)
        s_base = atomicAdd(cnt, s_wsum[0] + s_wsum[1] + s_wsum[2] + s_wsum[3]);
    __syncthreads();
    int wbase = 0;
    #pragma unroll
    for (int w = 0; w < 4; ++w)
        if (w < wave) wbase += s_wsum[w];
    pos[i] = m ? (s_base + wbase + wprefix) : -1;
}

// ---- per-row L2 normalize; write A (bf16), scatter masked scaled B ------
__global__ __launch_bounds__(256) void norm_kernel(
        const float* __restrict__ f0, const float* __restrict__ f1,
        const int* __restrict__ pos,
        u16* __restrict__ n0b, u16* __restrict__ Bc, float* __restrict__ wc,
        float* __restrict__ diag) {
    const int wave = threadIdx.x >> 6, lane = threadIdx.x & 63;
    const int i = blockIdx.x * 4 + wave;
    const float2 a = *(const float2*)(f0 + (size_t)i * DD + lane * 2);
    const float2 b = *(const float2*)(f1 + (size_t)i * DD + lane * 2);
    float s0 = a.x * a.x + a.y * a.y;
    float s1 = b.x * b.x + b.y * b.y;
    float d  = a.x * b.x + a.y * b.y;
    #pragma unroll
    for (int off = 32; off; off >>= 1) {
        s0 += __shfl_xor(s0, off);
        s1 += __shfl_xor(s1, off);
        d  += __shfl_xor(d,  off);
    }
    const float r0 = 1.0f / fmaxf(sqrtf(s0), 1e-12f);
    const float r1 = 1.0f / fmaxf(sqrtf(s1), 1e-12f);
    ushort2 t0; t0.x = f2bf(a.x * r0); t0.y = f2bf(a.y * r0);
    *(ushort2*)(n0b + (size_t)i * DD + lane * 2) = t0;
    const int p = pos[i];
    if (p >= 0) {
        const float sc = r1 * C_EXP2;
        ushort2 t1; t1.x = f2bf(b.x * sc); t1.y = f2bf(b.y * sc);
        *(ushort2*)(Bc + (size_t)p * DD + lane * 2) = t1;
        if (lane == 0) wc[p] = 1.0f;
    }
    if (lane == 0) diag[i] = d * r0 * r1;
}

// ---- B-tile DMA stage, source-swizzled (16B-chunk XOR, rule #21) --------
__device__ __forceinline__ void stage_tile(u16* dst, const u16* src,
                                           int wave, int lane) {
    char* lB = (char*)dst;
    const char* gB = (const char*)src;
    #pragma unroll
    for (int it = 0; it < 8; ++it) {
        const int ldsOff = it * 4096 + wave * 1024;      // wave-uniform base
        const int chunk  = (ldsOff >> 4) + lane;         // HW: dst + lane*16
        const int row    = chunk >> 4;
        const int c      = chunk & 15;
        const int srcOff = row * 256 + ((c ^ (row & 7)) << 4);
        __builtin_amdgcn_global_load_lds(
            (const __attribute__((address_space(1))) unsigned int*)(gB + srcOff),
            (__attribute__((address_space(3))) unsigned int*)(lB + ldsOff),
            16, 0, 0);
    }
}

// ---- main fused kernel: A-in-regs, B LDS double-buffered ----------------
// grid = (JSL, N/128). Block owns 128 i-rows × one j-slice of compacted cols.
// Wave tile 64x64 (2x2 wave grid). den accumulated in registers across the
// whole slice; epilogue: den += exp2(acc) * w   (B pre-scaled by C_EXP2).
__global__ __launch_bounds__(256, 2) void gemm_kernel(
        const u16* __restrict__ n0b, const u16* __restrict__ Bc,
        const float* __restrict__ wc, const int* __restrict__ cnt,
        float* __restrict__ den) {
    __shared__ u16 Bs[2][128 * 128];
    const int tid  = threadIdx.x;
    const int wave = tid >> 6, lane = tid & 63;
    const int jsl = blockIdx.x, iblk = blockIdx.y;
    const int wr = wave >> 1, wq = wave & 1;     // 2x2 wave grid
    const int lr = lane & 15, lk = lane >> 4;

    const int c = *cnt;
    const int ntiles = (c + 127) >> 7;
    const int per = (ntiles + JSL - 1) / JSL;
    const int t0 = jsl * per;
    const int t1 = min(ntiles, t0 + per);

    // A fragments: rows (iblk*128 + wr*64 + m*16 + lr), K chunk (kk*32+lk*8)
    bf16x8 af[4][4];
    #pragma unroll
    for (int m = 0; m < 4; ++m) {
        const int r = iblk * 128 + wr * 64 + m * 16 + lr;
        const char* rowp = (const char*)(n0b + (size_t)r * DD);
        #pragma unroll
        for (int kk = 0; kk < 4; ++kk)
            af[m][kk] = *(const bf16x8*)(rowp + kk * 64 + lk * 16);
    }

    float dacc[4][4] = {};   // [m][reg] per-lane col-partial denominators

    if (t0 < t1) {
        stage_tile(Bs[0], Bc + (size_t)t0 * DD * 128, wave, lane);
        __syncthreads();
        int cur = 0;
        for (int t = t0; t < t1; ++t) {
            if (t + 1 < t1)
                stage_tile(Bs[cur ^ 1], Bc + (size_t)(t + 1) * DD * 128, wave, lane);

            float wv[4];
            #pragma unroll
            for (int nn = 0; nn < 4; ++nn)
                wv[nn] = wc[t * 128 + wq * 64 + nn * 16 + lr];

            f32x4 acc[4][4] = {};
            const char* Bb = (const char*)Bs[cur];
            #pragma unroll
            for (int kk = 0; kk < 4; ++kk) {
                const int byteoff = kk * 64 + lk * 16;
                bf16x8 bfr[4];
                #pragma unroll
                for (int nn = 0; nn < 4; ++nn) {
                    const int rr = wq * 64 + nn * 16 + lr;
                    bfr[nn] = *(const bf16x8*)(Bb + rr * 256 + (byteoff ^ ((rr & 7) << 4)));
                }
                #pragma unroll
                for (int m = 0; m < 4; ++m)
                    #pragma unroll
                    for (int nn = 0; nn < 4; ++nn)
                        acc[m][nn] = __builtin_amdgcn_mfma_f32_16x16x32_bf16(
                                        af[m][kk], bfr[nn], acc[m][nn], 0, 0, 0);
            }

            // epilogue: den += exp2(sim*C) * w   (2 VALU ops / element)
            #pragma unroll
            for (int m = 0; m < 4; ++m)
                #pragma unroll
                for (int reg = 0; reg < 4; ++reg) {
                    float s = dacc[m][reg];
                    #pragma unroll
                    for (int nn = 0; nn < 4; ++nn)
                        s += fast_exp2(acc[m][nn][reg]) * wv[nn];
                    dacc[m][reg] = s;
                }
            __syncthreads();
            cur ^= 1;
        }
    }

    // reduce col-partials across the 16 lr-lanes; 1 atomic per (row, wave)
    #pragma unroll
    for (int m = 0; m < 4; ++m)
        #pragma unroll
        for (int reg = 0; reg < 4; ++reg) {
            float s = dacc[m][reg];
            s += __shfl_xor(s, 1);
            s += __shfl_xor(s, 2);
            s += __shfl_xor(s, 4);
            s += __shfl_xor(s, 8);
            if (lr == 0)
                atomicAdd(&den[iblk * 128 + wr * 64 + m * 16 + lk * 4 + reg], s);
        }
}

// ---- final masked loss: parallel partial reduce + double atomics --------
__global__ __launch_bounds__(256) void final1_kernel(
        const float* __restrict__ diag, const float* __restrict__ den,
        const float* __restrict__ maskf, double* __restrict__ accum) {
    const int i = blockIdx.x * 256 + threadIdx.x;
    double ls = 0.0, cs = 0.0;
    const float m = maskf[i];
    if (m != 0.0f) {
        const float num = expf(diag[i] * INV_T);
        const float l = logf(den[i] + 1e-8f) - logf(num + 1e-8f);
        ls = (double)l;
        cs = 1.0;
    }
    #pragma unroll
    for (int off = 32; off; off >>= 1) {
        ls += __shfl_xor(ls, off);
        cs += __shfl_xor(cs, off);
    }
    __shared__ double sl[4], sc[4];
    const int wave = threadIdx.x >> 6, lane = threadIdx.x & 63;
    if (lane == 0) { sl[wave] = ls; sc[wave] = cs; }
    __syncthreads();
    if (threadIdx.x == 0) {
        atomicAdd(&accum[0], sl[0] + sl[1] + sl[2] + sl[3]);
        atomicAdd(&accum[1], sc[0] + sc[1] + sc[2] + sc[3]);
    }
}

__global__ void final2_kernel(const double* __restrict__ accum,
                              float* __restrict__ out) {
    out[0] = (float)(accum[0] / accum[1]);
}

extern "C" void kernel_launch(void* const* d_in, const int* in_sizes, int n_in,
                              void* d_out, int out_size, void* d_ws, size_t ws_size,
                              hipStream_t stream) {
    const float* f0 = (const float*)d_in[0];
    const float* f1 = (const float*)d_in[1];
    const u8*  mraw = (const u8*)d_in[2];
    float* out = (float*)d_out;

    const int N = in_sizes[2];            // 16384
    char* ws = (char*)d_ws;
    u16*   n0b   = (u16*)ws;
    u16*   Bc    = (u16*)(ws + (size_t)4 * 1024 * 1024);
    float* diag  = (float*)(ws + (size_t)8 * 1024 * 1024);
    float* maskf = diag + N;
    float* wc    = maskf + N;
    float* den   = wc + N;
    int*   pos   = (int*)(den + N);
    int*   cnt   = (int*)(pos + N);       // 8-aligned
    double* accum = (double*)(cnt + 2);   // [0]=loss sum, [1]=count

    hipMemsetAsync(cnt, 0, 2 * sizeof(int) + 2 * sizeof(double), stream);
    prep_kernel<<<N / 256, 256, 0, stream>>>(mraw, maskf, wc, den, pos, cnt, N);
    norm_kernel<<<N / 4, 256, 0, stream>>>(f0, f1, pos, n0b, Bc, wc, diag);
    gemm_kernel<<<dim3(JSL, N / 128), 256, 0, stream>>>(n0b, Bc, wc, cnt, den);
    final1_kernel<<<N / 256, 256, 0, stream>>>(diag, den, maskf, accum);
    final2_kernel<<<1, 1, 0, stream>>>(accum, out);
}